// Round 3
// baseline (62.558 us; speedup 1.0000x reference)
//
#include <hip/hip_runtime.h>
#include <math.h>

#define B_SZ   32
#define T_LEN  500
#define VOCAB  8192
#define NBLK   (B_SZ * B_SZ)

// Fused: cross[i][j] = sum_t clip(x[j,t,Y[i,t]], -30, 30), then the last
// block to finish does the logsumexp finalize (device-scope counter).
__global__ __launch_bounds__(512)
void infonce_fused_kernel(const float* __restrict__ x,
                          const int*   __restrict__ Y,
                          const float* __restrict__ B_buf,
                          float*       __restrict__ out,
                          float*       __restrict__ cross,
                          unsigned*    __restrict__ counter) {
    const int j   = blockIdx.x;   // logits sample
    const int i   = blockIdx.y;   // target sample
    const int tid = threadIdx.x;

    // ---- gather phase: one scattered load per thread, max TLP ----
    float acc = 0.0f;
    if (tid < T_LEN) {
        const int y = Y[i * T_LEN + tid];                       // L2-hit after first j
        float v = x[(size_t)j * T_LEN * VOCAB + (size_t)tid * VOCAB + y];
        acc = fminf(fmaxf(v, -30.0f), 30.0f);
    }

    // wave reduce (64 lanes)
    #pragma unroll
    for (int off = 32; off > 0; off >>= 1)
        acc += __shfl_down(acc, off, 64);

    __shared__ float ws[8];
    __shared__ int   isLast;
    if ((tid & 63) == 0) ws[tid >> 6] = acc;
    __syncthreads();

    if (tid == 0) {
        float s = 0.0f;
        #pragma unroll
        for (int w = 0; w < 8; ++w) s += ws[w];
        __hip_atomic_store(&cross[i * B_SZ + j], s,
                           __ATOMIC_RELEASE, __HIP_MEMORY_SCOPE_AGENT);
        unsigned prev = __hip_atomic_fetch_add(counter, 1u,
                           __ATOMIC_ACQ_REL, __HIP_MEMORY_SCOPE_AGENT);
        isLast = (prev == NBLK - 1);
    }
    __syncthreads();
    if (!isLast) return;

    // ---- finalize phase (only in the last block; lanes 0..31) ----
    __shared__ float lt[B_SZ];
    if (tid < B_SZ) {
        // pass 1: row max
        float m = -INFINITY;
        #pragma unroll
        for (int jj = 0; jj < B_SZ; ++jj) {
            float c = __hip_atomic_load(&cross[tid * B_SZ + jj],
                          __ATOMIC_RELAXED, __HIP_MEMORY_SCOPE_AGENT);
            m = fmaxf(m, c);
        }
        // pass 2: exp-sum
        float s = 0.0f;
        #pragma unroll
        for (int jj = 0; jj < B_SZ; ++jj) {
            float c = __hip_atomic_load(&cross[tid * B_SZ + jj],
                          __ATOMIC_RELAXED, __HIP_MEMORY_SCOPE_AGENT);
            s += expf(c - m);
        }
        const float lse = m + logf(s);
        const float b0  = B_buf[0];
        const float hi  = fmaxf(lse, b0);
        const float lo  = fminf(lse, b0);
        const float den = hi + log1pf(expf(lo - hi));
        const float num = __hip_atomic_load(&cross[tid * B_SZ + tid],
                              __ATOMIC_RELAXED, __HIP_MEMORY_SCOPE_AGENT);
        lt[tid] = num - den;
    }
    __syncthreads();

    if (tid == 0) {
        float sum_lt = 0.0f, sum_exp = 0.0f;
        #pragma unroll
        for (int k = 0; k < B_SZ; ++k) {
            sum_lt  += lt[k];
            sum_exp += expf(lt[k]);
        }
        out[0] = -sum_lt / ((float)B_SZ * (float)T_LEN);  // loss
        out[1] = sum_exp * (float)T_LEN;                  // correct
    }
}

extern "C" void kernel_launch(void* const* d_in, const int* in_sizes, int n_in,
                              void* d_out, int out_size, void* d_ws, size_t ws_size,
                              hipStream_t stream) {
    const float* x     = (const float*)d_in[0];   // [32, 500, 8192] f32
    const int*   Y     = (const int*)  d_in[1];   // [32, 500]
    const float* B_buf = (const float*)d_in[2];   // [R+1]
    float*    out     = (float*)d_out;            // [loss, correct]
    float*    cross   = (float*)d_ws;             // 1024 f32 = 4 KB
    unsigned* counter = (unsigned*)((char*)d_ws + 4096);

    // zero the completion counter every call (graph-capture legal)
    hipMemsetAsync(counter, 0, sizeof(unsigned), stream);

    dim3 grid(B_SZ, B_SZ);
    infonce_fused_kernel<<<grid, 512, 0, stream>>>(x, Y, B_buf, out, cross, counter);
}

// Round 4
// 18.275 us; speedup vs baseline: 3.4231x; 3.4231x over previous
//
#include <hip/hip_runtime.h>
#include <math.h>

#define B_SZ   32
#define T_LEN  500
#define VOCAB  8192

// Kernel A: cross[i][j] = sum_t clip(x[j, t, Y[i, t]], -30, 30)
// One 256-thread block per (i,j). All loads hoisted & independent:
// 2 Y-loads then 2 x-gathers in flight simultaneously.
__global__ __launch_bounds__(256)
void infonce_cross_kernel(const float* __restrict__ x,
                          const int*   __restrict__ Y,
                          float*       __restrict__ cross) {
    const int j   = blockIdx.x;   // logits sample
    const int i   = blockIdx.y;   // target sample
    const int tid = threadIdx.x;

    const float* __restrict__ xj = x + (size_t)j * T_LEN * VOCAB;
    const int*   __restrict__ Yi = Y + i * T_LEN;

    const int  t0 = tid;          // < 500 always
    const int  t1 = tid + 256;
    const bool p1 = (t1 < T_LEN); // tid < 244

    // independent index loads (coalesced, L2-resident across the 32 j-blocks)
    const int y0 = Yi[t0];
    const int y1 = p1 ? Yi[t1] : 0;

    // independent scattered gathers
    const float v0 = xj[(size_t)t0 * VOCAB + y0];
    const float v1 = p1 ? xj[(size_t)t1 * VOCAB + y1] : 0.0f;

    float acc = fminf(fmaxf(v0, -30.0f), 30.0f);
    if (p1) acc += fminf(fmaxf(v1, -30.0f), 30.0f);

    // wave (64-lane) reduce
    #pragma unroll
    for (int off = 32; off > 0; off >>= 1)
        acc += __shfl_down(acc, off, 64);

    __shared__ float ws[4];
    if ((tid & 63) == 0) ws[tid >> 6] = acc;
    __syncthreads();
    if (tid == 0)
        cross[i * B_SZ + j] = ws[0] + ws[1] + ws[2] + ws[3];
}

// Kernel B: per-row logsumexp + logaddexp(B_buf[0]), then the two scalars.
// Single wave; lanes 0..31 own one row each, fully register-resident.
__global__ __launch_bounds__(64)
void infonce_finalize_kernel(const float* __restrict__ cross,
                             const float* __restrict__ B_buf,
                             float*       __restrict__ out) {
    const int lane = threadIdx.x;

    float lt = 0.0f;
    if (lane < B_SZ) {
        float r[B_SZ];
        #pragma unroll
        for (int jj = 0; jj < B_SZ; ++jj)
            r[jj] = cross[lane * B_SZ + jj];

        float m = -INFINITY;
        #pragma unroll
        for (int jj = 0; jj < B_SZ; ++jj)
            m = fmaxf(m, r[jj]);

        float s = 0.0f;
        #pragma unroll
        for (int jj = 0; jj < B_SZ; ++jj)
            s += expf(r[jj] - m);

        const float lse = m + logf(s);
        const float b0  = B_buf[0];
        const float hi  = fmaxf(lse, b0);
        const float lo  = fminf(lse, b0);
        const float den = hi + log1pf(expf(lo - hi));
        const float num = cross[lane * B_SZ + lane];  // separate load: keep r[] static-indexed
        lt = num - den;
    }

    float s_lt = (lane < B_SZ) ? lt        : 0.0f;
    float s_ex = (lane < B_SZ) ? expf(lt)  : 0.0f;
    // lanes 32..63 hold zeros; reduce lanes 0..31 into lane 0
    #pragma unroll
    for (int off = 16; off > 0; off >>= 1) {
        s_lt += __shfl_down(s_lt, off, 64);
        s_ex += __shfl_down(s_ex, off, 64);
    }

    if (lane == 0) {
        out[0] = -s_lt / ((float)B_SZ * (float)T_LEN);  // loss
        out[1] = s_ex * (float)T_LEN;                   // correct
    }
}

extern "C" void kernel_launch(void* const* d_in, const int* in_sizes, int n_in,
                              void* d_out, int out_size, void* d_ws, size_t ws_size,
                              hipStream_t stream) {
    const float* x     = (const float*)d_in[0];   // [32, 500, 8192] f32
    const int*   Y     = (const int*)  d_in[1];   // [32, 500]
    const float* B_buf = (const float*)d_in[2];   // [R+1]
    float* out   = (float*)d_out;                 // [loss, correct]
    float* cross = (float*)d_ws;                  // 32*32 f32 scratch

    dim3 grid(B_SZ, B_SZ);
    infonce_cross_kernel<<<grid, 256, 0, stream>>>(x, Y, cross);
    infonce_finalize_kernel<<<1, 64, 0, stream>>>(cross, B_buf, out);
}

// Round 5
// 18.118 us; speedup vs baseline: 3.4528x; 1.0087x over previous
//
#include <hip/hip_runtime.h>
#include <math.h>

#define B_SZ   32
#define T_LEN  500
#define VOCAB  8192

// Kernel A: cross[i][j] = sum_t clip(x[j, t, Y[i, t]], -30, 30)
// One 512-thread block per (i,j); exactly one gather per thread.
__global__ __launch_bounds__(512)
void infonce_cross_kernel(const float* __restrict__ x,
                          const int*   __restrict__ Y,
                          float*       __restrict__ cross) {
    const int j   = blockIdx.x;   // logits sample
    const int i   = blockIdx.y;   // target sample
    const int tid = threadIdx.x;

    float acc = 0.0f;
    if (tid < T_LEN) {
        const int y = Y[i * T_LEN + tid];   // coalesced, L2-resident across j
        const float v = x[(size_t)j * T_LEN * VOCAB + (size_t)tid * VOCAB + y];
        acc = fminf(fmaxf(v, -30.0f), 30.0f);
    }

    // wave (64-lane) reduce
    #pragma unroll
    for (int off = 32; off > 0; off >>= 1)
        acc += __shfl_down(acc, off, 64);

    __shared__ float ws[8];
    if ((tid & 63) == 0) ws[tid >> 6] = acc;
    __syncthreads();
    if (tid == 0) {
        float s = 0.0f;
        #pragma unroll
        for (int w = 0; w < 8; ++w) s += ws[w];
        cross[i * B_SZ + j] = s;
    }
}

// Kernel B: per-row logsumexp + logaddexp(B_buf[0]), then the two scalars.
// Single wave; lanes 0..31 own one row each, register-resident, 2-way ILP.
__global__ __launch_bounds__(64)
void infonce_finalize_kernel(const float* __restrict__ cross,
                             const float* __restrict__ B_buf,
                             float*       __restrict__ out) {
    const int lane = threadIdx.x;
    const float b0 = B_buf[0];                       // hoisted

    float lt = 0.0f;
    if (lane < B_SZ) {
        const float num = cross[lane * B_SZ + lane]; // hoisted diagonal load
        float r[B_SZ];
        #pragma unroll
        for (int jj = 0; jj < B_SZ; ++jj)
            r[jj] = cross[lane * B_SZ + jj];

        float m0 = -INFINITY, m1 = -INFINITY;
        #pragma unroll
        for (int jj = 0; jj < B_SZ; jj += 2) {
            m0 = fmaxf(m0, r[jj]);
            m1 = fmaxf(m1, r[jj + 1]);
        }
        const float m = fmaxf(m0, m1);

        float s0 = 0.0f, s1 = 0.0f;                  // 2-way ILP on expf chain
        #pragma unroll
        for (int jj = 0; jj < B_SZ; jj += 2) {
            s0 += expf(r[jj]     - m);
            s1 += expf(r[jj + 1] - m);
        }
        const float lse = m + logf(s0 + s1);

        const float hi  = fmaxf(lse, b0);
        const float lo  = fminf(lse, b0);
        const float den = hi + log1pf(expf(lo - hi));
        lt = num - den;
    }

    float s_lt = (lane < B_SZ) ? lt       : 0.0f;
    float s_ex = (lane < B_SZ) ? expf(lt) : 0.0f;
    #pragma unroll
    for (int off = 16; off > 0; off >>= 1) {
        s_lt += __shfl_down(s_lt, off, 64);
        s_ex += __shfl_down(s_ex, off, 64);
    }

    if (lane == 0) {
        out[0] = -s_lt / ((float)B_SZ * (float)T_LEN);  // loss
        out[1] = s_ex * (float)T_LEN;                   // correct
    }
}

extern "C" void kernel_launch(void* const* d_in, const int* in_sizes, int n_in,
                              void* d_out, int out_size, void* d_ws, size_t ws_size,
                              hipStream_t stream) {
    const float* x     = (const float*)d_in[0];   // [32, 500, 8192] f32
    const int*   Y     = (const int*)  d_in[1];   // [32, 500]
    const float* B_buf = (const float*)d_in[2];   // [R+1]
    float* out   = (float*)d_out;                 // [loss, correct]
    float* cross = (float*)d_ws;                  // 32*32 f32 scratch

    dim3 grid(B_SZ, B_SZ);
    infonce_cross_kernel<<<grid, 512, 0, stream>>>(x, Y, cross);
    infonce_finalize_kernel<<<1, 64, 0, stream>>>(cross, B_buf, out);
}